// Round 15
// baseline (285.821 us; speedup 1.0000x reference)
//
#include <hip/hip_runtime.h>
#include <math.h>

#define NBATCH 8
#define NFRAME 400
#define NHARM  100
#define NBAND  65
#define SRATE  16000
#define BLK    128
#define NSAMP  (NFRAME*BLK)      // 51200 samples per batch
#define PI_D   3.14159265358979323846

// FFT convolution params: overlap-save, FFT 4096, hop 2048, 8 imp partitions.
// Two real batches packed per complex FFT (imp real => conv is complex-linear).
#define FFTN   4096
#define HOP    2048
#define NPART  8
#define NHOPS  (NSAMP / HOP)     // 25 per batch
#define NPAIR  (NBATCH / 2)      // 4 batch-pairs
#define FTH    1024              // threads per block
#define GRID   200               // 200 blocks: co-residency guaranteed (3200 waves << 8192)

// workspace layout (byte offsets, 8B aligned)
#define OFF_SIG    25600         // float[8*51200]           = 1638400 B
#define OFF_H      1729536       // float2[8][4096]          = 262144 B
#define OFF_X      1991680       // float2[4*25][4096]       = 3276800 B
#define OFF_BAR    5268480       // unsigned[32]             = 128 B
// end ~5.3 MB

typedef float2 cplx;

__device__ __forceinline__ cplx cmul(cplx a, cplx b) {
    return make_float2(a.x * b.x - a.y * b.y, a.x * b.y + a.y * b.x);
}
// multiply by SIGN*i:  SIGN=-1: z*(-i) = (z.y, -z.x);  SIGN=+1: z*(+i) = (-z.y, z.x)
template <int SIGN>
__device__ __forceinline__ cplx rot90(cplx z) {
    return (SIGN < 0) ? make_float2(z.y, -z.x) : make_float2(-z.y, z.x);
}

// ---- software grid barrier (all GRID blocks co-resident by construction) ----
// Release: per-thread __threadfence (agent-scope wb) ; arrival via device-scope
// atomic; acquire: atomic load + per-thread __threadfence (inv stale L2 lines).
__device__ __forceinline__ void gbar(unsigned* ctr, unsigned target) {
    __threadfence();
    __syncthreads();
    if (threadIdx.x == 0) {
        __hip_atomic_fetch_add(ctr, 1u, __ATOMIC_ACQ_REL, __HIP_MEMORY_SCOPE_AGENT);
        while (__hip_atomic_load(ctr, __ATOMIC_ACQUIRE, __HIP_MEMORY_SCOPE_AGENT) < target)
            __builtin_amdgcn_s_sleep(2);
    }
    __syncthreads();
    __threadfence();
}

// ---- 4096-pt in-place complex FFT in LDS, 1024 threads, fused radix-2^2 ----
// One butterfly-group per thread per stage-pair.
// DIF (Gentleman-Sande): natural in -> digit-reversed out. SIGN=-1 forward.
template <int SIGN>
__device__ __forceinline__ void fft_dif_4096(cplx* A, int tid) {
    #pragma unroll
    for (int t = 12; t >= 2; t -= 2) {
        const int Q = 1 << (t - 2), h = 1 << (t - 1);
        __syncthreads();
        {
            int g = tid;                           // group idx [0,1024)
            int j = g & (Q - 1);
            int a = ((g >> (t - 2)) << t) + j;
            cplx x0 = A[a], x1 = A[a + Q], x2 = A[a + h], x3 = A[a + h + Q];
            float ang = (float)(2.0 * PI_D) * (float)j / (float)(1 << t);
            float sn, cs; __sincosf(ang, &sn, &cs);
            cplx w1 = make_float2(cs, (float)SIGN * sn);
            cplx w3 = make_float2(cs * cs - sn * sn, 2.0f * cs * sn * (float)SIGN);
            cplx p0 = make_float2(x0.x + x2.x, x0.y + x2.y);
            cplx p2 = cmul(make_float2(x0.x - x2.x, x0.y - x2.y), w1);
            cplx p1 = make_float2(x1.x + x3.x, x1.y + x3.y);
            cplx p3 = rot90<SIGN>(cmul(make_float2(x1.x - x3.x, x1.y - x3.y), w1));
            A[a]         = make_float2(p0.x + p1.x, p0.y + p1.y);
            A[a + Q]     = cmul(make_float2(p0.x - p1.x, p0.y - p1.y), w3);
            A[a + h]     = make_float2(p2.x + p3.x, p2.y + p3.y);
            A[a + h + Q] = cmul(make_float2(p2.x - p3.x, p2.y - p3.y), w3);
        }
    }
    __syncthreads();
}

// DIT (Cooley-Tukey): digit-reversed in -> natural out. SIGN=+1 inverse (unscaled).
template <int SIGN>
__device__ __forceinline__ void fft_dit_4096(cplx* A, int tid) {
    #pragma unroll
    for (int t = 2; t <= 12; t += 2) {
        const int Q = 1 << (t - 2), h = 1 << (t - 1);
        __syncthreads();
        {
            int g = tid;
            int j = g & (Q - 1);
            int a = ((g >> (t - 2)) << t) + j;
            cplx x0 = A[a], x1 = A[a + Q], x2 = A[a + h], x3 = A[a + h + Q];
            float ang = (float)(2.0 * PI_D) * (float)j / (float)(1 << t);
            float sn, cs; __sincosf(ang, &sn, &cs);
            cplx w1 = make_float2(cs, (float)SIGN * sn);
            cplx w3 = make_float2(cs * cs - sn * sn, 2.0f * cs * sn * (float)SIGN);
            cplx b1 = cmul(x1, w3);
            cplx q0 = make_float2(x0.x + b1.x, x0.y + b1.y);
            cplx q1 = make_float2(x0.x - b1.x, x0.y - b1.y);
            cplx b3 = cmul(x3, w3);
            cplx q2 = make_float2(x2.x + b3.x, x2.y + b3.y);
            cplx q3 = make_float2(x2.x - b3.x, x2.y - b3.y);
            cplx c2 = cmul(q2, w1);
            cplx c3 = rot90<SIGN>(cmul(q3, w1));
            A[a]         = make_float2(q0.x + c2.x, q0.y + c2.y);
            A[a + h]     = make_float2(q0.x - c2.x, q0.y - c2.y);
            A[a + Q]     = make_float2(q1.x + c3.x, q1.y + c3.y);
            A[a + h + Q] = make_float2(q1.x - c3.x, q1.y - c3.y);
        }
    }
    __syncthreads();
}

// scale_fn via explicit exp/log: 2*sigmoid(x)^log(10) + 1e-7
__device__ __forceinline__ float scale_fn(float x) {
    float s = 1.0f / (1.0f + __expf(-x));
    return 2.0f * __expf(2.3025851f * __logf(s)) + 1e-7f;
}

// per-group LDS state for one synth frame (8 groups per block)
struct SynthSmem {
    float famps[NHARM];
    float amps[NHARM];
    float np[NBAND];
    float ir[BLK];
    float nse[BLK];
    float red[BLK];
    double dred[BLK];
    float total;
};  // ~3632 B; x8 = ~29 KB <= 32 KB FFT region

// --- one frame of synth (lane = tid&127); __syncthreads are FULL-BLOCK and
// uniform across the 8 groups (identical fixed-trip control flow). ---
__device__ __forceinline__ void synth_frame(SynthSmem& S, int lane, int bf,
                                            const float* __restrict__ amp_param,
                                            const float* __restrict__ noise_param,
                                            const float* __restrict__ pitch,
                                            const float* __restrict__ noise,
                                            float* __restrict__ sig) {
    int b = bf / NFRAME, f0 = bf % NFRAME;
    float pf = pitch[bf];

    // prefix_excl = sum_{f < f0} pitch[b][f]  (fp64 tree reduce)
    {
        const float* prow = pitch + b * NFRAME;
        double ps = 0.0;
        for (int j = lane; j < f0; j += BLK) ps += (double)prow[j];
        S.dred[lane] = ps;
    }

    if (lane < NHARM + 1) {
        float p = scale_fn(amp_param[bf * (NHARM + 1) + lane]);
        if (lane == 0) S.total = p;
        else {
            float aa = (pf * (float)lane < 8000.0f) ? 1.0001f : 0.0001f;
            S.amps[lane - 1] = p * aa;
        }
    }
    if (lane < NBAND) S.np[lane] = scale_fn(noise_param[bf * NBAND + lane] - 5.0f);
    S.nse[lane] = noise[bf * BLK + lane];
    __syncthreads();

    for (int s = 64; s > 0; s >>= 1) {
        if (lane < s) S.dred[lane] += S.dred[lane + s];
        __syncthreads();
    }
    double prefix_b = S.dred[0];

    // ir[n]: 4 independent cosine chains (u_{k+4} = 2cos4a*u_k - u_{k-4})
    float irv;
    {
        float ang = (float)(2.0 * PI_D / 128.0) * (float)lane;
        float sn, c; __sincosf(ang, &sn, &c);
        float tcc = 2.0f * c;
        float u1 = c;
        float u2 = fmaf(tcc, u1, -1.0f);
        float u3 = fmaf(tcc, u2, -u1);
        float u4 = fmaf(tcc, u3, -u2);
        float u5 = fmaf(tcc, u4, -u3);
        float u6 = fmaf(tcc, u5, -u4);
        float u7 = fmaf(tcc, u6, -u5);
        float t0 = S.np[4] * u4;
        float t1 = fmaf(S.np[5], u5, S.np[1] * u1);
        float t2 = fmaf(S.np[6], u6, S.np[2] * u2);
        float t3 = fmaf(S.np[7], u7, S.np[3] * u3);
        float cc4  = fmaf(2.0f * u2, u2, -1.0f);
        float tc4a = 2.0f * cc4;
        float A0 = 1.0f, A1 = u1, A2 = u2, A3 = u3;
        float B0 = u4,   B1 = u5, B2 = u6, B3 = u7;
        #pragma unroll
        for (int g = 0; g < 14; ++g) {
            float n0 = fmaf(tc4a, B0, -A0); t0 = fmaf(S.np[8 + 4 * g + 0], n0, t0); A0 = B0; B0 = n0;
            float n1 = fmaf(tc4a, B1, -A1); t1 = fmaf(S.np[8 + 4 * g + 1], n1, t1); A1 = B1; B1 = n1;
            float n2 = fmaf(tc4a, B2, -A2); t2 = fmaf(S.np[8 + 4 * g + 2], n2, t2); A2 = B2; B2 = n2;
            float n3 = fmaf(tc4a, B3, -A3); t3 = fmaf(S.np[8 + 4 * g + 3], n3, t3); A3 = B3; B3 = n3;
        }
        float u64 = fmaf(tc4a, B0, -A0);
        float tt = (t0 + t1) + (t2 + t3);
        float a = fmaf(2.0f, tt, S.np[0]);
        a = fmaf(S.np[64], u64, a);
        a *= (1.0f / 128.0f);
        a *= fmaf(0.5f, c, 0.5f);
        irv = a;
    }

    // sum of masked amps (tree reduce over 128)
    S.red[lane] = (lane < NHARM) ? S.amps[lane] : 0.0f;
    __syncthreads();
    for (int s = 64; s > 0; s >>= 1) {
        if (lane < s) S.red[lane] += S.red[lane + s];
        __syncthreads();
    }
    float inv_red = S.red[0];
    __syncthreads();
    if (lane < NHARM) S.famps[lane] = S.amps[lane] / inv_red * S.total;
    S.ir[lane] = irv;
    __syncthreads();

    // nz[p] = sum_{m<=p} noise[m]*ir[p-m], balanced split, x2 unroll
    float accA = 0.0f;
    {
        int p1 = lane, h1 = (p1 + 2) >> 1;
        int m = 0;
        for (; m + 1 < h1; m += 2) {
            float i0 = S.ir[p1 - m], i1 = S.ir[p1 - m - 1];
            accA = fmaf(S.nse[m], i0, accA);
            accA = fmaf(S.nse[m + 1], i1, accA);
        }
        if (m < h1) accA = fmaf(S.nse[m], S.ir[p1 - m], accA);
    }
    {
        int p2 = 127 - lane, h2 = (p2 + 2) >> 1;
        float accB = 0.0f;
        int m = h2;
        for (; m + 1 <= p2; m += 2) {
            float i0 = S.ir[p2 - m], i1 = S.ir[p2 - m - 1];
            accB = fmaf(S.nse[m], i0, accB);
            accB = fmaf(S.nse[m + 1], i1, accB);
        }
        if (m <= p2) accB = fmaf(S.nse[m], S.ir[p2 - m], accB);
        S.red[p2] = accB;
    }
    __syncthreads();
    float nzv = accA + S.red[lane];

    // harmonic synth: 4 independent sin chains
    double q = (128.0 * prefix_b + (double)(lane + 1) * (double)pf) * (1.0 / 16000.0);
    float th = (float)(q - floor(q)) * (float)(2.0 * PI_D);
    float h;
    {
        float s1v, c1v; __sincosf(th, &s1v, &c1v);
        float tc = 2.0f * c1v;
        float sk0 = s1v;
        float sk1 = tc * s1v;
        float sk2 = fmaf(tc, sk1, -sk0);
        float sk3 = fmaf(tc, sk2, -sk1);
        float sk4 = fmaf(tc, sk3, -sk2);
        float sk5 = fmaf(tc, sk4, -sk3);
        float sk6 = fmaf(tc, sk5, -sk4);
        float sk7 = fmaf(tc, sk6, -sk5);
        float h0 = fmaf(sk4, S.famps[4], sk0 * S.famps[0]);
        float h1 = fmaf(sk5, S.famps[5], sk1 * S.famps[1]);
        float h2 = fmaf(sk6, S.famps[6], sk2 * S.famps[2]);
        float h3 = fmaf(sk7, S.famps[7], sk3 * S.famps[3]);
        float cs2 = fmaf(tc, c1v, -1.0f);
        float cs4 = fmaf(2.0f * cs2, cs2, -1.0f);
        float tc4 = 2.0f * cs4;
        float a0 = sk0, a1 = sk1, a2 = sk2, a3 = sk3;
        float b0 = sk4, b1 = sk5, b2 = sk6, b3 = sk7;
        #pragma unroll
        for (int g = 0; g < 23; ++g) {
            float n0 = fmaf(tc4, b0, -a0); h0 = fmaf(n0, S.famps[8 + 4 * g + 0], h0); a0 = b0; b0 = n0;
            float n1 = fmaf(tc4, b1, -a1); h1 = fmaf(n1, S.famps[8 + 4 * g + 1], h1); a1 = b1; b1 = n1;
            float n2 = fmaf(tc4, b2, -a2); h2 = fmaf(n2, S.famps[8 + 4 * g + 2], h2); a2 = b2; b2 = n2;
            float n3 = fmaf(tc4, b3, -a3); h3 = fmaf(n3, S.famps[8 + 4 * g + 3], h3); a3 = b3; b3 = n3;
        }
        h = (h0 + h1) + (h2 + h3);
    }
    sig[bf * BLK + lane] = h + nzv;
}

// --- fully fused: synth (all 200 blocks) | barrier | sigFFT(0..99)+HFFT(100..107)
//     | barrier | specmac+IFFT (0..99) ---
__global__ __launch_bounds__(FTH) void k_all(const float* __restrict__ amp_param,
                                             const float* __restrict__ noise_param,
                                             const float* __restrict__ pitch,
                                             const float* __restrict__ noise,
                                             const float* __restrict__ rn,
                                             const float* __restrict__ decay,
                                             const float* __restrict__ wet,
                                             float* __restrict__ sig,
                                             cplx* __restrict__ X,
                                             cplx* __restrict__ H,
                                             unsigned* __restrict__ bar,
                                             float* __restrict__ out) {
    __shared__ __align__(16) char smem[FFTN * sizeof(cplx)];   // 32 KB, phase-unioned
    int blk = blockIdx.x, tid = threadIdx.x;

    // ---- phase 0: synth, 8 concurrent frame-groups x 2 iterations = 16 frames/block ----
    {
        SynthSmem* Sg = reinterpret_cast<SynthSmem*>(smem) + (tid >> 7);
        int lane = tid & 127;
        #pragma unroll
        for (int it = 0; it < 2; ++it) {
            int bf = blk * 16 + it * 8 + (tid >> 7);   // 200*16 = 3200 exactly
            synth_frame(*Sg, lane, bf, amp_param, noise_param, pitch, noise, sig);
            __syncthreads();
        }
    }
    gbar(bar + 0, GRID);

    // ---- phase A: forward FFTs ----
    cplx* sA = reinterpret_cast<cplx*>(smem);
    if (blk < NPAIR * NHOPS) {
        int pb = blk / NHOPS, m = blk % NHOPS;
        const float* sa = sig + (2 * pb) * NSAMP;
        const float* sb = sa + NSAMP;
        int base = HOP * (m - 1);
        for (int i = tid; i < FFTN; i += FTH) {
            int idx = base + i;                      // idx < NSAMP guaranteed (m<=24)
            float va = 0.0f, vb = 0.0f;
            if (idx >= 0) { va = sa[idx]; vb = sb[idx]; }
            sA[i] = make_float2(va, vb);
        }
        fft_dif_4096<-1>(sA, tid);
        for (int i = tid; i < FFTN; i += FTH) X[blk * FFTN + i] = sA[i];
    } else if (blk < NPAIR * NHOPS + NPART) {
        int p = blk - NPAIR * NHOPS;
        double c  = log1p(exp(-(double)decay[0])) * (500.0 / (double)SRATE);
        double wg = 1.0 / (1.0 + exp(-(double)wet[0]));
        for (int i = tid; i < FFTN; i += FTH) {
            float v = 0.0f;
            if (i < HOP) {
                int t = p * HOP + i;
                if (t == 0)         v = 1.0f;
                else if (t < SRATE) v = rn[t] * (float)(exp(-c * (double)t) * wg);
            }
            sA[i] = make_float2(v, 0.0f);
        }
        fft_dif_4096<-1>(sA, tid);
        const float s = 1.0f / (float)FFTN;     // fold IFFT scale into H
        for (int i = tid; i < FFTN; i += FTH) {
            cplx v = sA[i];
            H[p * FFTN + i] = make_float2(v.x * s, v.y * s);
        }
    }
    gbar(bar + 16, GRID);

    // ---- phase B: spectral MAC + inverse FFT + output ----
    if (blk < NPAIR * NHOPS) {
        int pb = blk / NHOPS, m = blk % NHOPS;
        cplx acc[4];
        #pragma unroll
        for (int it = 0; it < 4; ++it) acc[it] = make_float2(0.0f, 0.0f);

        int pmax = (m < NPART - 1) ? m : (NPART - 1);
        for (int p = 0; p <= pmax; ++p) {
            const cplx* Xm = X + (pb * NHOPS + (m - p)) * FFTN;
            const cplx* Hp = H + p * FFTN;
            #pragma unroll
            for (int it = 0; it < 4; ++it) {
                int i = tid + (it << 10);
                cplx xv = Xm[i], hv = Hp[i];
                cplx pr = cmul(xv, hv);
                acc[it].x += pr.x; acc[it].y += pr.y;
            }
        }
        #pragma unroll
        for (int it = 0; it < 4; ++it) sA[tid + (it << 10)] = acc[it];

        fft_dit_4096<1>(sA, tid);      // digit-rev in -> natural out (scale in H)

        float* ob0 = out + (2 * pb) * NSAMP + m * HOP;
        float* ob1 = ob0 + NSAMP;
        #pragma unroll
        for (int it = 0; it < 2; ++it) {
            int j = tid + (it << 10);                // [0,2048)
            cplx v = sA[HOP + j];                    // discard first half (overlap-save)
            ob0[j] = v.x;
            ob1[j] = v.y;
        }
    }
}

extern "C" void kernel_launch(void* const* d_in, const int* in_sizes, int n_in,
                              void* d_out, int out_size, void* d_ws, size_t ws_size,
                              hipStream_t stream) {
    const float* amp_param   = (const float*)d_in[0];
    const float* noise_param = (const float*)d_in[1];
    const float* pitch       = (const float*)d_in[2];
    const float* noise       = (const float*)d_in[3];
    const float* rn          = (const float*)d_in[4];
    const float* decay       = (const float*)d_in[5];
    const float* wet         = (const float*)d_in[6];
    float* out = (float*)d_out;

    char* ws = (char*)d_ws;
    float*    sig = (float*)(ws + OFF_SIG);
    cplx*     H   = (cplx*)(ws + OFF_H);
    cplx*     X   = (cplx*)(ws + OFF_X);
    unsigned* bar = (unsigned*)(ws + OFF_BAR);

    hipMemsetAsync(bar, 0, 128, stream);
    k_all<<<dim3(GRID), dim3(FTH), 0, stream>>>(amp_param, noise_param, pitch, noise,
                                                rn, decay, wet, sig, X, H, bar, out);
}

// Round 16
// 39.487 us; speedup vs baseline: 7.2383x; 7.2383x over previous
//
#include <hip/hip_runtime.h>
#include <math.h>

#define NBATCH 8
#define NFRAME 400
#define NHARM  100
#define NBAND  65
#define SRATE  16000
#define BLK    128
#define NSAMP  (NFRAME*BLK)      // 51200 samples per batch
#define PI_D   3.14159265358979323846

// FFT convolution params: overlap-save, FFT 4096, hop 2048, 8 imp partitions.
// Two real batches packed per complex FFT (imp real => conv is complex-linear).
#define FFTN   4096
#define HOP    2048
#define NPART  8
#define NHOPS  (NSAMP / HOP)     // 25 per batch
#define NPAIR  (NBATCH / 2)      // 4 batch-pairs
#define FTH    1024              // threads per FFT block (latency-bound: 1 group/thread/pass)
#define NCONV  (NPAIR * NHOPS)   // 100 conv blocks

// workspace layout (byte offsets, 8B aligned)
#define OFF_SIG    25600         // float[8*51200]           = 1638400 B
#define OFF_H      1729536       // float2[8][4096]          = 262144 B
#define OFF_X      1991680       // float2[4*25][4096]       = 3276800 B
// end 5268480 (~5.3 MB)

typedef float2 cplx;

// XCD-chunked bijective swizzle (T1): consecutive bm land on one XCD for both
// the X-writer (k_fftsig) and X-reader (k_specmac_ifft) kernels, so specmac's
// X[m-7..m] re-reads hit that XCD's private L2 instead of HBM.
// nwg=100, 8 XCDs: q=12, r=4 (m204 bijective-chunked form).
__device__ __forceinline__ int conv_swz(int bid) {
    int xcd = bid & 7, idx = bid >> 3;
    int base = (xcd < 4) ? xcd * 13 : 52 + (xcd - 4) * 12;
    return base + idx;
}

__device__ __forceinline__ cplx cmul(cplx a, cplx b) {
    return make_float2(a.x * b.x - a.y * b.y, a.x * b.y + a.y * b.x);
}
// multiply by SIGN*i:  SIGN=-1: z*(-i) = (z.y, -z.x);  SIGN=+1: z*(+i) = (-z.y, z.x)
template <int SIGN>
__device__ __forceinline__ cplx rot90(cplx z) {
    return (SIGN < 0) ? make_float2(z.y, -z.x) : make_float2(-z.y, z.x);
}

// ---- 4096-pt in-place complex FFT in LDS, FTH=1024 threads, fused radix-2^2 ----
// One butterfly-group per thread per stage-pair (1024 groups).
// DIF (Gentleman-Sande): natural in -> digit-reversed out. SIGN=-1 forward.
template <int SIGN>
__device__ __forceinline__ void fft_dif_4096(cplx* A, int tid) {
    #pragma unroll
    for (int t = 12; t >= 2; t -= 2) {
        const int Q = 1 << (t - 2), h = 1 << (t - 1);
        __syncthreads();
        {
            int g = tid;                           // group idx [0,1024)
            int j = g & (Q - 1);
            int a = ((g >> (t - 2)) << t) + j;
            cplx x0 = A[a], x1 = A[a + Q], x2 = A[a + h], x3 = A[a + h + Q];
            float ang = (float)(2.0 * PI_D) * (float)j / (float)(1 << t);
            float sn, cs; __sincosf(ang, &sn, &cs);
            cplx w1 = make_float2(cs, (float)SIGN * sn);
            cplx w3 = make_float2(cs * cs - sn * sn, 2.0f * cs * sn * (float)SIGN);
            // stage t
            cplx p0 = make_float2(x0.x + x2.x, x0.y + x2.y);
            cplx p2 = cmul(make_float2(x0.x - x2.x, x0.y - x2.y), w1);
            cplx p1 = make_float2(x1.x + x3.x, x1.y + x3.y);
            cplx p3 = rot90<SIGN>(cmul(make_float2(x1.x - x3.x, x1.y - x3.y), w1));
            // stage t-1
            A[a]         = make_float2(p0.x + p1.x, p0.y + p1.y);
            A[a + Q]     = cmul(make_float2(p0.x - p1.x, p0.y - p1.y), w3);
            A[a + h]     = make_float2(p2.x + p3.x, p2.y + p3.y);
            A[a + h + Q] = cmul(make_float2(p2.x - p3.x, p2.y - p3.y), w3);
        }
    }
    __syncthreads();
}

// DIT (Cooley-Tukey): digit-reversed in -> natural out. SIGN=+1 inverse (unscaled).
template <int SIGN>
__device__ __forceinline__ void fft_dit_4096(cplx* A, int tid) {
    #pragma unroll
    for (int t = 2; t <= 12; t += 2) {
        const int Q = 1 << (t - 2), h = 1 << (t - 1);
        __syncthreads();
        {
            int g = tid;
            int j = g & (Q - 1);
            int a = ((g >> (t - 2)) << t) + j;
            cplx x0 = A[a], x1 = A[a + Q], x2 = A[a + h], x3 = A[a + h + Q];
            float ang = (float)(2.0 * PI_D) * (float)j / (float)(1 << t);
            float sn, cs; __sincosf(ang, &sn, &cs);
            cplx w1 = make_float2(cs, (float)SIGN * sn);
            cplx w3 = make_float2(cs * cs - sn * sn, 2.0f * cs * sn * (float)SIGN);
            // stage t-1
            cplx b1 = cmul(x1, w3);
            cplx q0 = make_float2(x0.x + b1.x, x0.y + b1.y);
            cplx q1 = make_float2(x0.x - b1.x, x0.y - b1.y);
            cplx b3 = cmul(x3, w3);
            cplx q2 = make_float2(x2.x + b3.x, x2.y + b3.y);
            cplx q3 = make_float2(x2.x - b3.x, x2.y - b3.y);
            // stage t
            cplx c2 = cmul(q2, w1);
            cplx c3 = rot90<SIGN>(cmul(q3, w1));
            A[a]         = make_float2(q0.x + c2.x, q0.y + c2.y);
            A[a + h]     = make_float2(q0.x - c2.x, q0.y - c2.y);
            A[a + Q]     = make_float2(q1.x + c3.x, q1.y + c3.y);
            A[a + h + Q] = make_float2(q1.x - c3.x, q1.y - c3.y);
        }
    }
    __syncthreads();
}

// scale_fn via explicit exp/log (powf is ~40 inst): 2*sigmoid(x)^log(10) + 1e-7
__device__ __forceinline__ float scale_fn(float x) {
    float s = 1.0f / (1.0f + __expf(-x));
    return 2.0f * __expf(2.3025851f * __logf(s)) + 1e-7f;
}

// --- fused per-(b,f) frame processing + harmonic synth -> signal ---
// Self-contained: pitch prefix computed per block via fp64 tree reduction.
__global__ __launch_bounds__(128) void k_synth(const float* __restrict__ amp_param,
                                               const float* __restrict__ noise_param,
                                               const float* __restrict__ pitch,
                                               const float* __restrict__ noise,
                                               float* __restrict__ sig) {
    __shared__ float s_famps[NHARM];   // normalized amps (phase-2 input)
    __shared__ float s_amps[NHARM];    // masked raw amps
    __shared__ float s_np[NBAND];
    __shared__ float s_ir[BLK];
    __shared__ float s_noise[BLK];
    __shared__ float s_red[BLK];       // reduction temps, then nz partials
    __shared__ double s_dred[BLK];     // fp64 prefix reduction
    __shared__ float s_total;

    int bf = blockIdx.x;
    int tid = threadIdx.x;
    int b  = bf / NFRAME, f0 = bf % NFRAME;
    float pf = pitch[bf];

    // prefix_excl = sum_{f < f0} pitch[b][f]  (fp64 tree reduce, <=4 loads/thread)
    {
        const float* prow = pitch + b * NFRAME;
        double ps = 0.0;
        for (int j = tid; j < f0; j += BLK) ps += (double)prow[j];
        s_dred[tid] = ps;
    }

    if (tid < NHARM + 1) {
        float p = scale_fn(amp_param[bf * (NHARM + 1) + tid]);
        if (tid == 0) s_total = p;
        else {
            // aa = (pitch*k < sr/2) + 1e-4  -> 1.0001 or 0.0001, k = tid
            float aa = (pf * (float)tid < 8000.0f) ? 1.0001f : 0.0001f;
            s_amps[tid - 1] = p * aa;
        }
    }
    if (tid < NBAND) s_np[tid] = scale_fn(noise_param[bf * NBAND + tid] - 5.0f);
    s_noise[tid] = noise[bf * BLK + tid];
    __syncthreads();

    // fold fp64 prefix reduction into the first sync ladder
    for (int s = 64; s > 0; s >>= 1) {
        if (tid < s) s_dred[tid] += s_dred[tid + s];
        __syncthreads();
    }
    double prefix_b = s_dred[0];

    // ir[n] = (1/128)*(np[0] + 2*sum_{k=1}^{63} np[k] cos(2pi k n/128) + np[64] cos(pi n))
    //         * (0.5 + 0.5*cos(2pi n/128))    [roll/hann/roll collapsed]
    // 4 independent cosine chains: u_{k+4} = 2cos(4a)*u_k - u_{k-4}  (ILP for dep latency)
    float irv;
    {
        float ang = (float)(2.0 * PI_D / 128.0) * (float)tid;
        float sn, c; __sincosf(ang, &sn, &c);
        float tcc = 2.0f * c;
        float u1 = c;
        float u2 = fmaf(tcc, u1, -1.0f);
        float u3 = fmaf(tcc, u2, -u1);
        float u4 = fmaf(tcc, u3, -u2);
        float u5 = fmaf(tcc, u4, -u3);
        float u6 = fmaf(tcc, u5, -u4);
        float u7 = fmaf(tcc, u6, -u5);
        float t0 = s_np[4] * u4;
        float t1 = fmaf(s_np[5], u5, s_np[1] * u1);
        float t2 = fmaf(s_np[6], u6, s_np[2] * u2);
        float t3 = fmaf(s_np[7], u7, s_np[3] * u3);
        float cc4  = fmaf(2.0f * u2, u2, -1.0f);   // cos(4a)
        float tc4a = 2.0f * cc4;
        float A0 = 1.0f, A1 = u1, A2 = u2, A3 = u3;   // u_{k-8}
        float B0 = u4,   B1 = u5, B2 = u6, B3 = u7;   // u_{k-4}
        #pragma unroll
        for (int g = 0; g < 14; ++g) {                // k = 8+4g+i, i=0..3 -> 8..63
            float n0 = fmaf(tc4a, B0, -A0); t0 = fmaf(s_np[8 + 4 * g + 0], n0, t0); A0 = B0; B0 = n0;
            float n1 = fmaf(tc4a, B1, -A1); t1 = fmaf(s_np[8 + 4 * g + 1], n1, t1); A1 = B1; B1 = n1;
            float n2 = fmaf(tc4a, B2, -A2); t2 = fmaf(s_np[8 + 4 * g + 2], n2, t2); A2 = B2; B2 = n2;
            float n3 = fmaf(tc4a, B3, -A3); t3 = fmaf(s_np[8 + 4 * g + 3], n3, t3); A3 = B3; B3 = n3;
        }
        float u64 = fmaf(tc4a, B0, -A0);              // chain0 state: B0=u60, A0=u56
        float tt = (t0 + t1) + (t2 + t3);
        float a = fmaf(2.0f, tt, s_np[0]);
        a = fmaf(s_np[64], u64, a);
        a *= (1.0f / 128.0f);
        a *= fmaf(0.5f, c, 0.5f);
        irv = a;
    }

    // sum of masked amps (tree reduce over 128, entries >=100 are 0)
    s_red[tid] = (tid < NHARM) ? s_amps[tid] : 0.0f;
    __syncthreads();
    for (int s = 64; s > 0; s >>= 1) {
        if (tid < s) s_red[tid] += s_red[tid + s];
        __syncthreads();
    }
    float inv_red = s_red[0];
    __syncthreads();                   // s_red reads done; reuse as nz partials
    if (tid < NHARM) s_famps[tid] = s_amps[tid] / inv_red * s_total;
    s_ir[tid] = irv;
    __syncthreads();

    // nz[p] = sum_{m<=p} noise[m] * ir[p-m], balanced split, m unrolled x2 so
    // adjacent s_ir reads fuse into ds_read2_b32 (same FP order as before).
    float accA = 0.0f;
    {
        int p1 = tid, h1 = (p1 + 2) >> 1;          // ceil((p1+1)/2)
        int m = 0;
        for (; m + 1 < h1; m += 2) {
            float i0 = s_ir[p1 - m], i1 = s_ir[p1 - m - 1];
            accA = fmaf(s_noise[m], i0, accA);
            accA = fmaf(s_noise[m + 1], i1, accA);
        }
        if (m < h1) accA = fmaf(s_noise[m], s_ir[p1 - m], accA);
    }
    {
        int p2 = 127 - tid, h2 = (p2 + 2) >> 1;
        float accB = 0.0f;
        int m = h2;
        for (; m + 1 <= p2; m += 2) {
            float i0 = s_ir[p2 - m], i1 = s_ir[p2 - m - 1];
            accB = fmaf(s_noise[m], i0, accB);
            accB = fmaf(s_noise[m + 1], i1, accB);
        }
        if (m <= p2) accB = fmaf(s_noise[m], s_ir[p2 - m], accB);
        s_red[p2] = accB;
    }
    __syncthreads();
    float nzv = accA + s_red[tid];

    // harmonic synth: omega[n]/2pi = (128*prefix_excl + (r+1)*pitch)/sr; th = 2pi*frac
    // h = sum_k sin(k*th)*famps[k-1]; 4 independent sin chains:
    // s_{k+4} = 2cos(4th)*s_k - s_{k-4}  (seeds s1..s8)
    double q = (128.0 * prefix_b + (double)(tid + 1) * (double)pf) * (1.0 / 16000.0);
    float th = (float)(q - floor(q)) * (float)(2.0 * PI_D);  // exact for integer-k harmonics
    float h;
    {
        float s1v, c1v; __sincosf(th, &s1v, &c1v);
        float tc = 2.0f * c1v;
        float sk0 = s1v;                       // s1
        float sk1 = tc * s1v;                  // s2 (s0 = 0)
        float sk2 = fmaf(tc, sk1, -sk0);
        float sk3 = fmaf(tc, sk2, -sk1);
        float sk4 = fmaf(tc, sk3, -sk2);
        float sk5 = fmaf(tc, sk4, -sk3);
        float sk6 = fmaf(tc, sk5, -sk4);
        float sk7 = fmaf(tc, sk6, -sk5);
        float h0 = fmaf(sk4, s_famps[4], sk0 * s_famps[0]);
        float h1 = fmaf(sk5, s_famps[5], sk1 * s_famps[1]);
        float h2 = fmaf(sk6, s_famps[6], sk2 * s_famps[2]);
        float h3 = fmaf(sk7, s_famps[7], sk3 * s_famps[3]);
        float cs2 = fmaf(tc, c1v, -1.0f);      // cos(2th)
        float cs4 = fmaf(2.0f * cs2, cs2, -1.0f);
        float tc4 = 2.0f * cs4;
        float a0 = sk0, a1 = sk1, a2 = sk2, a3 = sk3;
        float b0 = sk4, b1 = sk5, b2 = sk6, b3 = sk7;
        #pragma unroll
        for (int g = 0; g < 23; ++g) {         // k = 9+4g+i, i=0..3 -> 9..100
            float n0 = fmaf(tc4, b0, -a0); h0 = fmaf(n0, s_famps[8 + 4 * g + 0], h0); a0 = b0; b0 = n0;
            float n1 = fmaf(tc4, b1, -a1); h1 = fmaf(n1, s_famps[8 + 4 * g + 1], h1); a1 = b1; b1 = n1;
            float n2 = fmaf(tc4, b2, -a2); h2 = fmaf(n2, s_famps[8 + 4 * g + 2], h2); a2 = b2; b2 = n2;
            float n3 = fmaf(tc4, b3, -a3); h3 = fmaf(n3, s_famps[8 + 4 * g + 3], h3); a3 = b3; b3 = n3;
        }
        h = (h0 + h1) + (h2 + h3);
    }
    sig[bf * BLK + tid] = h + nzv;
}

// --- FFT of packed signal frames (blocks 0..99, XCD-chunk-swizzled):
//     X[bm] = DIF_FFT(sigA + i*sigB)
//     + impulse-partition FFTs (blocks 100..107): H[p], scaled by 1/FFTN ---
__global__ __launch_bounds__(FTH) void k_fftsig(const float* __restrict__ sig,
                                                const float* __restrict__ rn,
                                                const float* __restrict__ decay,
                                                const float* __restrict__ wet,
                                                cplx* __restrict__ X,
                                                cplx* __restrict__ H) {
    __shared__ cplx sA[FFTN];
    int bid = blockIdx.x;
    int tid = threadIdx.x;

    if (bid >= NCONV) {
        // impulse partition p
        int p = bid - NCONV;
        double c  = log1p(exp(-(double)decay[0])) * (500.0 / (double)SRATE);
        double wg = 1.0 / (1.0 + exp(-(double)wet[0]));
        for (int i = tid; i < FFTN; i += FTH) {
            float v = 0.0f;
            if (i < HOP) {
                int t = p * HOP + i;
                if (t == 0)         v = 1.0f;
                else if (t < SRATE) v = rn[t] * (float)(exp(-c * (double)t) * wg);
            }
            sA[i] = make_float2(v, 0.0f);
        }
        fft_dif_4096<-1>(sA, tid);
        const float s = 1.0f / (float)FFTN;     // fold IFFT scale into H
        for (int i = tid; i < FFTN; i += FTH) {
            cplx v = sA[i];
            H[p * FFTN + i] = make_float2(v.x * s, v.y * s);
        }
        return;
    }

    int bm = conv_swz(bid);                      // same map as specmac -> X stays in-XCD L2
    int pb = bm / NHOPS, m = bm % NHOPS;
    const float* sa = sig + (2 * pb) * NSAMP;
    const float* sb = sa + NSAMP;
    int base = HOP * (m - 1);
    for (int i = tid; i < FFTN; i += FTH) {
        int idx = base + i;                      // idx < NSAMP guaranteed (m<=24)
        float va = 0.0f, vb = 0.0f;
        if (idx >= 0) { va = sa[idx]; vb = sb[idx]; }
        sA[i] = make_float2(va, vb);
    }
    fft_dif_4096<-1>(sA, tid);
    for (int i = tid; i < FFTN; i += FTH) X[bm * FFTN + i] = sA[i];
}

// --- Y = sum_p X[pb][m-p]*H[p] (digit-rev), IFFT, Re->batch 2pb, Im->batch 2pb+1 ---
__global__ __launch_bounds__(FTH) void k_specmac_ifft(const cplx* __restrict__ X,
                                                      const cplx* __restrict__ H,
                                                      float* __restrict__ out) {
    __shared__ cplx sA[FFTN];
    int bm = conv_swz(blockIdx.x);               // same map as fftsig (T1 locality)
    int pb = bm / NHOPS, m = bm % NHOPS;
    int tid = threadIdx.x;

    cplx acc[4];
    #pragma unroll
    for (int it = 0; it < 4; ++it) acc[it] = make_float2(0.0f, 0.0f);

    int pmax = (m < NPART - 1) ? m : (NPART - 1);
    for (int p = 0; p <= pmax; ++p) {
        const cplx* Xm = X + (pb * NHOPS + (m - p)) * FFTN;
        const cplx* Hp = H + p * FFTN;
        #pragma unroll
        for (int it = 0; it < 4; ++it) {
            int i = tid + (it << 10);
            cplx xv = Xm[i], hv = Hp[i];
            cplx pr = cmul(xv, hv);
            acc[it].x += pr.x; acc[it].y += pr.y;
        }
    }
    #pragma unroll
    for (int it = 0; it < 4; ++it) sA[tid + (it << 10)] = acc[it];

    fft_dit_4096<1>(sA, tid);      // digit-rev in -> natural out (scale folded into H)

    float* ob0 = out + (2 * pb) * NSAMP + m * HOP;
    float* ob1 = ob0 + NSAMP;
    #pragma unroll
    for (int it = 0; it < 2; ++it) {
        int j = tid + (it << 10);                // [0,2048)
        cplx v = sA[HOP + j];                    // discard first half (overlap-save)
        ob0[j] = v.x;
        ob1[j] = v.y;
    }
}

extern "C" void kernel_launch(void* const* d_in, const int* in_sizes, int n_in,
                              void* d_out, int out_size, void* d_ws, size_t ws_size,
                              hipStream_t stream) {
    const float* amp_param   = (const float*)d_in[0];
    const float* noise_param = (const float*)d_in[1];
    const float* pitch       = (const float*)d_in[2];
    const float* noise       = (const float*)d_in[3];
    const float* rn          = (const float*)d_in[4];
    const float* decay       = (const float*)d_in[5];
    const float* wet         = (const float*)d_in[6];
    float* out = (float*)d_out;

    char* ws = (char*)d_ws;
    float*  sig    = (float*)(ws + OFF_SIG);
    cplx*   H      = (cplx*)(ws + OFF_H);
    cplx*   X      = (cplx*)(ws + OFF_X);

    k_synth<<<dim3(NBATCH * NFRAME), dim3(128), 0, stream>>>(amp_param, noise_param, pitch, noise, sig);
    k_fftsig<<<dim3(NCONV + NPART), dim3(FTH), 0, stream>>>(sig, rn, decay, wet, X, H);
    k_specmac_ifft<<<dim3(NCONV), dim3(FTH), 0, stream>>>(X, H, out);
}

// Round 17
// 37.499 us; speedup vs baseline: 7.6221x; 1.0530x over previous
//
#include <hip/hip_runtime.h>
#include <math.h>

#define NBATCH 8
#define NFRAME 400
#define NHARM  100
#define NBAND  65
#define SRATE  16000
#define BLK    128
#define NSAMP  (NFRAME*BLK)      // 51200 samples per batch
#define PI_D   3.14159265358979323846

// FFT convolution params: overlap-save, FFT 4096, hop 2048, 8 imp partitions.
// Two real batches packed per complex FFT (imp real => conv is complex-linear).
#define FFTN   4096
#define HOP    2048
#define NPART  8
#define NHOPS  (NSAMP / HOP)     // 25 per batch
#define NPAIR  (NBATCH / 2)      // 4 batch-pairs
#define FTH    1024              // threads per FFT block (latency-bound: 1 group/thread/pass)
#define NCONV  (NPAIR * NHOPS)   // 100 conv blocks

// workspace layout (byte offsets, 8B aligned)
#define OFF_SIG    25600         // float[8*51200]           = 1638400 B
#define OFF_H      1729536       // float2[8][4096]          = 262144 B
#define OFF_X      1991680       // float2[4*25][4096]       = 3276800 B
// end 5268480 (~5.3 MB)

typedef float2 cplx;

// XCD-chunked bijective swizzle (T1): consecutive bm land on one XCD for both
// the X-writer (k_fftsig) and X-reader (k_specmac_ifft) kernels, so specmac's
// X[m-7..m] re-reads hit that XCD's private L2 instead of HBM.
// nwg=100, 8 XCDs: q=12, r=4 (m204 bijective-chunked form).
__device__ __forceinline__ int conv_swz(int bid) {
    int xcd = bid & 7, idx = bid >> 3;
    int base = (xcd < 4) ? xcd * 13 : 52 + (xcd - 4) * 12;
    return base + idx;
}

__device__ __forceinline__ cplx cmul(cplx a, cplx b) {
    return make_float2(a.x * b.x - a.y * b.y, a.x * b.y + a.y * b.x);
}
// multiply by SIGN*i:  SIGN=-1: z*(-i) = (z.y, -z.x);  SIGN=+1: z*(+i) = (-z.y, z.x)
template <int SIGN>
__device__ __forceinline__ cplx rot90(cplx z) {
    return (SIGN < 0) ? make_float2(z.y, -z.x) : make_float2(-z.y, z.x);
}

// ---- 4096-pt in-place complex FFT in LDS, FTH=1024 threads, fused radix-2^2 ----
// One butterfly-group per thread per stage-pair (1024 groups).
// DIF (Gentleman-Sande): natural in -> digit-reversed out. SIGN=-1 forward.
template <int SIGN>
__device__ __forceinline__ void fft_dif_4096(cplx* A, int tid) {
    #pragma unroll
    for (int t = 12; t >= 2; t -= 2) {
        const int Q = 1 << (t - 2), h = 1 << (t - 1);
        __syncthreads();
        {
            int g = tid;                           // group idx [0,1024)
            int j = g & (Q - 1);
            int a = ((g >> (t - 2)) << t) + j;
            cplx x0 = A[a], x1 = A[a + Q], x2 = A[a + h], x3 = A[a + h + Q];
            float ang = (float)(2.0 * PI_D) * (float)j / (float)(1 << t);
            float sn, cs; __sincosf(ang, &sn, &cs);
            cplx w1 = make_float2(cs, (float)SIGN * sn);
            cplx w3 = make_float2(cs * cs - sn * sn, 2.0f * cs * sn * (float)SIGN);
            // stage t
            cplx p0 = make_float2(x0.x + x2.x, x0.y + x2.y);
            cplx p2 = cmul(make_float2(x0.x - x2.x, x0.y - x2.y), w1);
            cplx p1 = make_float2(x1.x + x3.x, x1.y + x3.y);
            cplx p3 = rot90<SIGN>(cmul(make_float2(x1.x - x3.x, x1.y - x3.y), w1));
            // stage t-1
            A[a]         = make_float2(p0.x + p1.x, p0.y + p1.y);
            A[a + Q]     = cmul(make_float2(p0.x - p1.x, p0.y - p1.y), w3);
            A[a + h]     = make_float2(p2.x + p3.x, p2.y + p3.y);
            A[a + h + Q] = cmul(make_float2(p2.x - p3.x, p2.y - p3.y), w3);
        }
    }
    __syncthreads();
}

// DIT (Cooley-Tukey): digit-reversed in -> natural out. SIGN=+1 inverse (unscaled).
template <int SIGN>
__device__ __forceinline__ void fft_dit_4096(cplx* A, int tid) {
    #pragma unroll
    for (int t = 2; t <= 12; t += 2) {
        const int Q = 1 << (t - 2), h = 1 << (t - 1);
        __syncthreads();
        {
            int g = tid;
            int j = g & (Q - 1);
            int a = ((g >> (t - 2)) << t) + j;
            cplx x0 = A[a], x1 = A[a + Q], x2 = A[a + h], x3 = A[a + h + Q];
            float ang = (float)(2.0 * PI_D) * (float)j / (float)(1 << t);
            float sn, cs; __sincosf(ang, &sn, &cs);
            cplx w1 = make_float2(cs, (float)SIGN * sn);
            cplx w3 = make_float2(cs * cs - sn * sn, 2.0f * cs * sn * (float)SIGN);
            // stage t-1
            cplx b1 = cmul(x1, w3);
            cplx q0 = make_float2(x0.x + b1.x, x0.y + b1.y);
            cplx q1 = make_float2(x0.x - b1.x, x0.y - b1.y);
            cplx b3 = cmul(x3, w3);
            cplx q2 = make_float2(x2.x + b3.x, x2.y + b3.y);
            cplx q3 = make_float2(x2.x - b3.x, x2.y - b3.y);
            // stage t
            cplx c2 = cmul(q2, w1);
            cplx c3 = rot90<SIGN>(cmul(q3, w1));
            A[a]         = make_float2(q0.x + c2.x, q0.y + c2.y);
            A[a + h]     = make_float2(q0.x - c2.x, q0.y - c2.y);
            A[a + Q]     = make_float2(q1.x + c3.x, q1.y + c3.y);
            A[a + h + Q] = make_float2(q1.x - c3.x, q1.y - c3.y);
        }
    }
    __syncthreads();
}

// scale_fn via explicit exp/log (powf is ~40 inst): 2*sigmoid(x)^log(10) + 1e-7
__device__ __forceinline__ float scale_fn(float x) {
    float s = 1.0f / (1.0f + __expf(-x));
    return 2.0f * __expf(2.3025851f * __logf(s)) + 1e-7f;
}

// --- fused per-(b,f) frame processing + harmonic synth -> signal ---
// 3-barrier version: amps-sum + fp64 pitch-prefix reduced via wave64
// __shfl_xor butterflies (no LDS ladder; each thread owns its own amps value).
__global__ __launch_bounds__(128) void k_synth(const float* __restrict__ amp_param,
                                               const float* __restrict__ noise_param,
                                               const float* __restrict__ pitch,
                                               const float* __restrict__ noise,
                                               float* __restrict__ sig) {
    __shared__ float s_famps[NHARM];   // normalized amps (phase-2 input)
    __shared__ float s_np[NBAND];
    __shared__ float s_ir[BLK];
    __shared__ float s_noise[BLK];
    __shared__ float s_red[BLK];       // nz partials
    __shared__ double s_dsum[2];       // per-wave fp64 prefix sums
    __shared__ float s_fsum[2];        // per-wave amps sums
    __shared__ float s_total;

    int bf = blockIdx.x;
    int tid = threadIdx.x;
    int b  = bf / NFRAME, f0 = bf % NFRAME;
    float pf = pitch[bf];

    // fp64 prefix partial: sum_{f < f0} pitch[b][f]
    double ps = 0.0;
    {
        const float* prow = pitch + b * NFRAME;
        for (int j = tid; j < f0; j += BLK) ps += (double)prow[j];
    }

    // own masked amp (harmonic tid-1); no LDS staging needed for the sum
    float myamp = 0.0f;
    if (tid < NHARM + 1) {
        float p = scale_fn(amp_param[bf * (NHARM + 1) + tid]);
        if (tid == 0) s_total = p;
        else {
            // aa = (pitch*k < sr/2) + 1e-4  -> 1.0001 or 0.0001, k = tid
            float aa = (pf * (float)tid < 8000.0f) ? 1.0001f : 0.0001f;
            myamp = p * aa;
        }
    }
    if (tid < NBAND) s_np[tid] = scale_fn(noise_param[bf * NBAND + tid] - 5.0f);
    s_noise[tid] = noise[bf * BLK + tid];

    // wave64 butterfly allreduce of (ps, myamp); then one cross-wave exchange
    double rp = ps; float ra = myamp;
    #pragma unroll
    for (int off = 32; off >= 1; off >>= 1) {
        rp += __shfl_xor(rp, off);
        ra += __shfl_xor(ra, off);
    }
    if ((tid & 63) == 0) { s_dsum[tid >> 6] = rp; s_fsum[tid >> 6] = ra; }
    __syncthreads();                   // barrier 1: staging + wave sums + s_total

    double prefix_b = s_dsum[0] + s_dsum[1];
    float red = s_fsum[0] + s_fsum[1];
    if (tid >= 1 && tid <= NHARM) s_famps[tid - 1] = myamp / red * s_total;

    // ir[n] = (1/128)*(np[0] + 2*sum_{k=1}^{63} np[k] cos(2pi k n/128) + np[64] cos(pi n))
    //         * (0.5 + 0.5*cos(2pi n/128))    [roll/hann/roll collapsed]
    // 4 independent cosine chains: u_{k+4} = 2cos(4a)*u_k - u_{k-4}  (ILP for dep latency)
    float irv;
    {
        float ang = (float)(2.0 * PI_D / 128.0) * (float)tid;
        float sn, c; __sincosf(ang, &sn, &c);
        float tcc = 2.0f * c;
        float u1 = c;
        float u2 = fmaf(tcc, u1, -1.0f);
        float u3 = fmaf(tcc, u2, -u1);
        float u4 = fmaf(tcc, u3, -u2);
        float u5 = fmaf(tcc, u4, -u3);
        float u6 = fmaf(tcc, u5, -u4);
        float u7 = fmaf(tcc, u6, -u5);
        float t0 = s_np[4] * u4;
        float t1 = fmaf(s_np[5], u5, s_np[1] * u1);
        float t2 = fmaf(s_np[6], u6, s_np[2] * u2);
        float t3 = fmaf(s_np[7], u7, s_np[3] * u3);
        float cc4  = fmaf(2.0f * u2, u2, -1.0f);   // cos(4a)
        float tc4a = 2.0f * cc4;
        float A0 = 1.0f, A1 = u1, A2 = u2, A3 = u3;   // u_{k-8}
        float B0 = u4,   B1 = u5, B2 = u6, B3 = u7;   // u_{k-4}
        #pragma unroll
        for (int g = 0; g < 14; ++g) {                // k = 8+4g+i, i=0..3 -> 8..63
            float n0 = fmaf(tc4a, B0, -A0); t0 = fmaf(s_np[8 + 4 * g + 0], n0, t0); A0 = B0; B0 = n0;
            float n1 = fmaf(tc4a, B1, -A1); t1 = fmaf(s_np[8 + 4 * g + 1], n1, t1); A1 = B1; B1 = n1;
            float n2 = fmaf(tc4a, B2, -A2); t2 = fmaf(s_np[8 + 4 * g + 2], n2, t2); A2 = B2; B2 = n2;
            float n3 = fmaf(tc4a, B3, -A3); t3 = fmaf(s_np[8 + 4 * g + 3], n3, t3); A3 = B3; B3 = n3;
        }
        float u64 = fmaf(tc4a, B0, -A0);              // chain0 state: B0=u60, A0=u56
        float tt = (t0 + t1) + (t2 + t3);
        float a = fmaf(2.0f, tt, s_np[0]);
        a = fmaf(s_np[64], u64, a);
        a *= (1.0f / 128.0f);
        a *= fmaf(0.5f, c, 0.5f);
        irv = a;
    }
    s_ir[tid] = irv;
    __syncthreads();                   // barrier 2: s_ir + s_famps visible

    // nz[p] = sum_{m<=p} noise[m] * ir[p-m], balanced split, m unrolled x2 so
    // adjacent s_ir reads fuse into ds_read2_b32 (same FP order as before).
    float accA = 0.0f;
    {
        int p1 = tid, h1 = (p1 + 2) >> 1;          // ceil((p1+1)/2)
        int m = 0;
        for (; m + 1 < h1; m += 2) {
            float i0 = s_ir[p1 - m], i1 = s_ir[p1 - m - 1];
            accA = fmaf(s_noise[m], i0, accA);
            accA = fmaf(s_noise[m + 1], i1, accA);
        }
        if (m < h1) accA = fmaf(s_noise[m], s_ir[p1 - m], accA);
    }
    {
        int p2 = 127 - tid, h2 = (p2 + 2) >> 1;
        float accB = 0.0f;
        int m = h2;
        for (; m + 1 <= p2; m += 2) {
            float i0 = s_ir[p2 - m], i1 = s_ir[p2 - m - 1];
            accB = fmaf(s_noise[m], i0, accB);
            accB = fmaf(s_noise[m + 1], i1, accB);
        }
        if (m <= p2) accB = fmaf(s_noise[m], s_ir[p2 - m], accB);
        s_red[p2] = accB;
    }
    __syncthreads();                   // barrier 3: nz partials
    float nzv = accA + s_red[tid];

    // harmonic synth: omega[n]/2pi = (128*prefix_excl + (r+1)*pitch)/sr; th = 2pi*frac
    // h = sum_k sin(k*th)*famps[k-1]; 4 independent sin chains:
    // s_{k+4} = 2cos(4th)*s_k - s_{k-4}  (seeds s1..s8)
    double q = (128.0 * prefix_b + (double)(tid + 1) * (double)pf) * (1.0 / 16000.0);
    float th = (float)(q - floor(q)) * (float)(2.0 * PI_D);  // exact for integer-k harmonics
    float h;
    {
        float s1v, c1v; __sincosf(th, &s1v, &c1v);
        float tc = 2.0f * c1v;
        float sk0 = s1v;                       // s1
        float sk1 = tc * s1v;                  // s2 (s0 = 0)
        float sk2 = fmaf(tc, sk1, -sk0);
        float sk3 = fmaf(tc, sk2, -sk1);
        float sk4 = fmaf(tc, sk3, -sk2);
        float sk5 = fmaf(tc, sk4, -sk3);
        float sk6 = fmaf(tc, sk5, -sk4);
        float sk7 = fmaf(tc, sk6, -sk5);
        float h0 = fmaf(sk4, s_famps[4], sk0 * s_famps[0]);
        float h1 = fmaf(sk5, s_famps[5], sk1 * s_famps[1]);
        float h2 = fmaf(sk6, s_famps[6], sk2 * s_famps[2]);
        float h3 = fmaf(sk7, s_famps[7], sk3 * s_famps[3]);
        float cs2 = fmaf(tc, c1v, -1.0f);      // cos(2th)
        float cs4 = fmaf(2.0f * cs2, cs2, -1.0f);
        float tc4 = 2.0f * cs4;
        float a0 = sk0, a1 = sk1, a2 = sk2, a3 = sk3;
        float b0 = sk4, b1 = sk5, b2 = sk6, b3 = sk7;
        #pragma unroll
        for (int g = 0; g < 23; ++g) {         // k = 9+4g+i, i=0..3 -> 9..100
            float n0 = fmaf(tc4, b0, -a0); h0 = fmaf(n0, s_famps[8 + 4 * g + 0], h0); a0 = b0; b0 = n0;
            float n1 = fmaf(tc4, b1, -a1); h1 = fmaf(n1, s_famps[8 + 4 * g + 1], h1); a1 = b1; b1 = n1;
            float n2 = fmaf(tc4, b2, -a2); h2 = fmaf(n2, s_famps[8 + 4 * g + 2], h2); a2 = b2; b2 = n2;
            float n3 = fmaf(tc4, b3, -a3); h3 = fmaf(n3, s_famps[8 + 4 * g + 3], h3); a3 = b3; b3 = n3;
        }
        h = (h0 + h1) + (h2 + h3);
    }
    sig[bf * BLK + tid] = h + nzv;
}

// --- FFT of packed signal frames (blocks 0..99, XCD-chunk-swizzled):
//     X[bm] = DIF_FFT(sigA + i*sigB)
//     + impulse-partition FFTs (blocks 100..107): H[p], scaled by 1/FFTN ---
__global__ __launch_bounds__(FTH) void k_fftsig(const float* __restrict__ sig,
                                                const float* __restrict__ rn,
                                                const float* __restrict__ decay,
                                                const float* __restrict__ wet,
                                                cplx* __restrict__ X,
                                                cplx* __restrict__ H) {
    __shared__ cplx sA[FFTN];
    int bid = blockIdx.x;
    int tid = threadIdx.x;

    if (bid >= NCONV) {
        // impulse partition p
        int p = bid - NCONV;
        double c  = log1p(exp(-(double)decay[0])) * (500.0 / (double)SRATE);
        double wg = 1.0 / (1.0 + exp(-(double)wet[0]));
        for (int i = tid; i < FFTN; i += FTH) {
            float v = 0.0f;
            if (i < HOP) {
                int t = p * HOP + i;
                if (t == 0)         v = 1.0f;
                else if (t < SRATE) v = rn[t] * (float)(exp(-c * (double)t) * wg);
            }
            sA[i] = make_float2(v, 0.0f);
        }
        fft_dif_4096<-1>(sA, tid);
        const float s = 1.0f / (float)FFTN;     // fold IFFT scale into H
        for (int i = tid; i < FFTN; i += FTH) {
            cplx v = sA[i];
            H[p * FFTN + i] = make_float2(v.x * s, v.y * s);
        }
        return;
    }

    int bm = conv_swz(bid);                      // same map as specmac -> X stays in-XCD L2
    int pb = bm / NHOPS, m = bm % NHOPS;
    const float* sa = sig + (2 * pb) * NSAMP;
    const float* sb = sa + NSAMP;
    int base = HOP * (m - 1);
    for (int i = tid; i < FFTN; i += FTH) {
        int idx = base + i;                      // idx < NSAMP guaranteed (m<=24)
        float va = 0.0f, vb = 0.0f;
        if (idx >= 0) { va = sa[idx]; vb = sb[idx]; }
        sA[i] = make_float2(va, vb);
    }
    fft_dif_4096<-1>(sA, tid);
    for (int i = tid; i < FFTN; i += FTH) X[bm * FFTN + i] = sA[i];
}

// --- Y = sum_p X[pb][m-p]*H[p] (digit-rev), IFFT, Re->batch 2pb, Im->batch 2pb+1 ---
__global__ __launch_bounds__(FTH) void k_specmac_ifft(const cplx* __restrict__ X,
                                                      const cplx* __restrict__ H,
                                                      float* __restrict__ out) {
    __shared__ cplx sA[FFTN];
    int bm = conv_swz(blockIdx.x);               // same map as fftsig (T1 locality)
    int pb = bm / NHOPS, m = bm % NHOPS;
    int tid = threadIdx.x;

    cplx acc[4];
    #pragma unroll
    for (int it = 0; it < 4; ++it) acc[it] = make_float2(0.0f, 0.0f);

    int pmax = (m < NPART - 1) ? m : (NPART - 1);
    for (int p = 0; p <= pmax; ++p) {
        const cplx* Xm = X + (pb * NHOPS + (m - p)) * FFTN;
        const cplx* Hp = H + p * FFTN;
        #pragma unroll
        for (int it = 0; it < 4; ++it) {
            int i = tid + (it << 10);
            cplx xv = Xm[i], hv = Hp[i];
            cplx pr = cmul(xv, hv);
            acc[it].x += pr.x; acc[it].y += pr.y;
        }
    }
    #pragma unroll
    for (int it = 0; it < 4; ++it) sA[tid + (it << 10)] = acc[it];

    fft_dit_4096<1>(sA, tid);      // digit-rev in -> natural out (scale folded into H)

    float* ob0 = out + (2 * pb) * NSAMP + m * HOP;
    float* ob1 = ob0 + NSAMP;
    #pragma unroll
    for (int it = 0; it < 2; ++it) {
        int j = tid + (it << 10);                // [0,2048)
        cplx v = sA[HOP + j];                    // discard first half (overlap-save)
        ob0[j] = v.x;
        ob1[j] = v.y;
    }
}

extern "C" void kernel_launch(void* const* d_in, const int* in_sizes, int n_in,
                              void* d_out, int out_size, void* d_ws, size_t ws_size,
                              hipStream_t stream) {
    const float* amp_param   = (const float*)d_in[0];
    const float* noise_param = (const float*)d_in[1];
    const float* pitch       = (const float*)d_in[2];
    const float* noise       = (const float*)d_in[3];
    const float* rn          = (const float*)d_in[4];
    const float* decay       = (const float*)d_in[5];
    const float* wet         = (const float*)d_in[6];
    float* out = (float*)d_out;

    char* ws = (char*)d_ws;
    float*  sig    = (float*)(ws + OFF_SIG);
    cplx*   H      = (cplx*)(ws + OFF_H);
    cplx*   X      = (cplx*)(ws + OFF_X);

    k_synth<<<dim3(NBATCH * NFRAME), dim3(128), 0, stream>>>(amp_param, noise_param, pitch, noise, sig);
    k_fftsig<<<dim3(NCONV + NPART), dim3(FTH), 0, stream>>>(sig, rn, decay, wet, X, H);
    k_specmac_ifft<<<dim3(NCONV), dim3(FTH), 0, stream>>>(X, H, out);
}

// Round 18
// 36.036 us; speedup vs baseline: 7.9314x; 1.0406x over previous
//
#include <hip/hip_runtime.h>
#include <math.h>

#define NBATCH 8
#define NFRAME 400
#define NHARM  100
#define NBAND  65
#define SRATE  16000
#define BLK    128
#define NSAMP  (NFRAME*BLK)      // 51200 samples per batch
#define PI_D   3.14159265358979323846
#define C8     0.70710678118654752f   // sqrt(2)/2

// FFT convolution params: overlap-save, FFT 4096, hop 2048, 8 imp partitions.
// Two real batches packed per complex FFT (imp real => conv is complex-linear).
#define FFTN   4096
#define HOP    2048
#define NPART  8
#define NHOPS  (NSAMP / HOP)     // 25 per batch
#define NPAIR  (NBATCH / 2)      // 4 batch-pairs
#define FTH    512               // threads per FFT block (radix-8: 512 groups/pass)
#define NCONV  (NPAIR * NHOPS)   // 100 conv blocks

// workspace layout (byte offsets, 8B aligned)
#define OFF_SIG    25600         // float[8*51200]           = 1638400 B
#define OFF_H      1729536       // float2[8][4096]          = 262144 B
#define OFF_X      1991680       // float2[4*25][4096]       = 3276800 B
// end 5268480 (~5.3 MB)

typedef float2 cplx;

// XCD-chunked bijective swizzle (T1): consecutive bm land on one XCD for both
// the X-writer (k_fftsig) and X-reader (k_specmac_ifft) kernels, so specmac's
// X[m-7..m] re-reads hit that XCD's private L2 instead of HBM.
__device__ __forceinline__ int conv_swz(int bid) {
    int xcd = bid & 7, idx = bid >> 3;
    int base = (xcd < 4) ? xcd * 13 : 52 + (xcd - 4) * 12;
    return base + idx;
}

__device__ __forceinline__ cplx cmul(cplx a, cplx b) {
    return make_float2(a.x * b.x - a.y * b.y, a.x * b.y + a.y * b.x);
}
__device__ __forceinline__ cplx cadd(cplx a, cplx b) { return make_float2(a.x + b.x, a.y + b.y); }
__device__ __forceinline__ cplx csub(cplx a, cplx b) { return make_float2(a.x - b.x, a.y - b.y); }
// multiply by e^{SIGN*i*pi/2}:  SIGN=-1: z*(-i) = (z.y, -z.x);  SIGN=+1: z*(+i) = (-z.y, z.x)
template <int SIGN>
__device__ __forceinline__ cplx rot90(cplx z) {
    return (SIGN < 0) ? make_float2(z.y, -z.x) : make_float2(-z.y, z.x);
}
// multiply by omega_8 = e^{SIGN*i*pi/4}
template <int SIGN>
__device__ __forceinline__ cplx mul_w8(cplx z) {
    return (SIGN < 0) ? make_float2(C8 * (z.x + z.y), C8 * (z.y - z.x))
                      : make_float2(C8 * (z.x - z.y), C8 * (z.y + z.x));
}

// 8-point DFT in place: out_k = sum_m v[m] * e^{SIGN*2pi*i*k*m/8}.
// Verified on delta_0 (all-ones) and delta_1 (omega_8^k ladder).
template <int SIGN>
__device__ __forceinline__ void dft8(cplx v[8]) {
    cplx s0 = cadd(v[0], v[4]), s1 = cadd(v[1], v[5]);
    cplx s2 = cadd(v[2], v[6]), s3 = cadd(v[3], v[7]);
    cplx d0 = csub(v[0], v[4]), d1 = csub(v[1], v[5]);
    cplx d2 = csub(v[2], v[6]), d3 = csub(v[3], v[7]);
    // even outputs: DFT4(s)
    cplx t0 = cadd(s0, s2), t1 = csub(s0, s2), t2 = cadd(s1, s3), t3 = csub(s1, s3);
    cplx E0 = cadd(t0, t2), E2 = csub(t0, t2);
    cplx r3 = rot90<SIGN>(t3);
    cplx E1 = cadd(t1, r3), E3 = csub(t1, r3);
    // odd outputs: DFT4(d'), d' = {d0, w8*d1, rot90*d2, rot90(w8*d3)}
    cplx o1 = mul_w8<SIGN>(d1);
    cplx o2 = rot90<SIGN>(d2);
    cplx o3 = rot90<SIGN>(mul_w8<SIGN>(d3));
    cplx u0 = cadd(d0, o2), u1 = csub(d0, o2), u2 = cadd(o1, o3), u3 = csub(o1, o3);
    cplx O0 = cadd(u0, u2), O2 = csub(u0, u2);
    cplx r7 = rot90<SIGN>(u3);
    cplx O1 = cadd(u1, r7), O3 = csub(u1, r7);
    v[0] = E0; v[2] = E1; v[4] = E2; v[6] = E3;
    v[1] = O0; v[3] = O1; v[5] = O2; v[7] = O3;
}

// ---- 4096-pt in-place complex FFT in LDS, 512 threads, radix-8 (4 passes) ----
// DIF (Gentleman-Sande): natural in -> base-8-digit-reversed out. SIGN=-1 forward.
// Stage t (len L=2^t, Q=L/8): y_k = DFT8(x)_k * w^k, w = e^{SIGN*2pi*i*j/L}.
template <int SIGN>
__device__ __forceinline__ void fft8_dif(cplx* A, int tid) {
    #pragma unroll
    for (int t = 12; t >= 3; t -= 3) {
        const int Q = 1 << (t - 3);
        __syncthreads();
        int j = tid & (Q - 1);
        int a = ((tid >> (t - 3)) << t) + j;
        cplx v[8];
        #pragma unroll
        for (int k = 0; k < 8; ++k) v[k] = A[a + k * Q];
        dft8<SIGN>(v);
        float ang = (float)(2.0 * PI_D) * (float)j / (float)(1 << t);
        float sn, cs; __sincosf(ang, &sn, &cs);
        cplx w1 = make_float2(cs, (float)SIGN * sn);
        cplx w2 = cmul(w1, w1);
        cplx w3 = cmul(w2, w1);
        cplx w4 = cmul(w2, w2);
        cplx w5 = cmul(w4, w1);
        cplx w6 = cmul(w4, w2);
        cplx w7 = cmul(w4, w3);
        A[a]         = v[0];
        A[a + Q]     = cmul(v[1], w1);
        A[a + 2 * Q] = cmul(v[2], w2);
        A[a + 3 * Q] = cmul(v[3], w3);
        A[a + 4 * Q] = cmul(v[4], w4);
        A[a + 5 * Q] = cmul(v[5], w5);
        A[a + 6 * Q] = cmul(v[6], w6);
        A[a + 7 * Q] = cmul(v[7], w7);
    }
    __syncthreads();
}

// DIT (Cooley-Tukey): digit-reversed in -> natural out. SIGN=+1 inverse (unscaled;
// x8 per stage, 8^4=4096 total, folded into H). Exact stage-by-stage inverse of
// fft8_dif run in reverse stage order: z_k = y_k*w^k (SIGN=+1), x_m = DFT8+(z)_m.
template <int SIGN>
__device__ __forceinline__ void fft8_dit(cplx* A, int tid) {
    #pragma unroll
    for (int t = 3; t <= 12; t += 3) {
        const int Q = 1 << (t - 3);
        __syncthreads();
        int j = tid & (Q - 1);
        int a = ((tid >> (t - 3)) << t) + j;
        float ang = (float)(2.0 * PI_D) * (float)j / (float)(1 << t);
        float sn, cs; __sincosf(ang, &sn, &cs);
        cplx w1 = make_float2(cs, (float)SIGN * sn);
        cplx w2 = cmul(w1, w1);
        cplx w3 = cmul(w2, w1);
        cplx w4 = cmul(w2, w2);
        cplx w5 = cmul(w4, w1);
        cplx w6 = cmul(w4, w2);
        cplx w7 = cmul(w4, w3);
        cplx v[8];
        v[0] = A[a];
        v[1] = cmul(A[a + Q], w1);
        v[2] = cmul(A[a + 2 * Q], w2);
        v[3] = cmul(A[a + 3 * Q], w3);
        v[4] = cmul(A[a + 4 * Q], w4);
        v[5] = cmul(A[a + 5 * Q], w5);
        v[6] = cmul(A[a + 6 * Q], w6);
        v[7] = cmul(A[a + 7 * Q], w7);
        dft8<SIGN>(v);
        #pragma unroll
        for (int k = 0; k < 8; ++k) A[a + k * Q] = v[k];
    }
    __syncthreads();
}

// scale_fn via explicit exp/log (powf is ~40 inst): 2*sigmoid(x)^log(10) + 1e-7
__device__ __forceinline__ float scale_fn(float x) {
    float s = 1.0f / (1.0f + __expf(-x));
    return 2.0f * __expf(2.3025851f * __logf(s)) + 1e-7f;
}

// --- fused per-(b,f) frame processing + harmonic synth -> signal ---
// 3-barrier version: amps-sum + fp64 pitch-prefix reduced via wave64
// __shfl_xor butterflies (no LDS ladder; each thread owns its own amps value).
__global__ __launch_bounds__(128) void k_synth(const float* __restrict__ amp_param,
                                               const float* __restrict__ noise_param,
                                               const float* __restrict__ pitch,
                                               const float* __restrict__ noise,
                                               float* __restrict__ sig) {
    __shared__ float s_famps[NHARM];   // normalized amps (phase-2 input)
    __shared__ float s_np[NBAND];
    __shared__ float s_ir[BLK];
    __shared__ float s_noise[BLK];
    __shared__ float s_red[BLK];       // nz partials
    __shared__ double s_dsum[2];       // per-wave fp64 prefix sums
    __shared__ float s_fsum[2];        // per-wave amps sums
    __shared__ float s_total;

    int bf = blockIdx.x;
    int tid = threadIdx.x;
    int b  = bf / NFRAME, f0 = bf % NFRAME;
    float pf = pitch[bf];

    // fp64 prefix partial: sum_{f < f0} pitch[b][f]
    double ps = 0.0;
    {
        const float* prow = pitch + b * NFRAME;
        for (int j = tid; j < f0; j += BLK) ps += (double)prow[j];
    }

    // own masked amp (harmonic tid-1); no LDS staging needed for the sum
    float myamp = 0.0f;
    if (tid < NHARM + 1) {
        float p = scale_fn(amp_param[bf * (NHARM + 1) + tid]);
        if (tid == 0) s_total = p;
        else {
            // aa = (pitch*k < sr/2) + 1e-4  -> 1.0001 or 0.0001, k = tid
            float aa = (pf * (float)tid < 8000.0f) ? 1.0001f : 0.0001f;
            myamp = p * aa;
        }
    }
    if (tid < NBAND) s_np[tid] = scale_fn(noise_param[bf * NBAND + tid] - 5.0f);
    s_noise[tid] = noise[bf * BLK + tid];

    // wave64 butterfly allreduce of (ps, myamp); then one cross-wave exchange
    double rp = ps; float ra = myamp;
    #pragma unroll
    for (int off = 32; off >= 1; off >>= 1) {
        rp += __shfl_xor(rp, off);
        ra += __shfl_xor(ra, off);
    }
    if ((tid & 63) == 0) { s_dsum[tid >> 6] = rp; s_fsum[tid >> 6] = ra; }
    __syncthreads();                   // barrier 1: staging + wave sums + s_total

    double prefix_b = s_dsum[0] + s_dsum[1];
    float red = s_fsum[0] + s_fsum[1];
    if (tid >= 1 && tid <= NHARM) s_famps[tid - 1] = myamp / red * s_total;

    // ir[n] = (1/128)*(np[0] + 2*sum_{k=1}^{63} np[k] cos(2pi k n/128) + np[64] cos(pi n))
    //         * (0.5 + 0.5*cos(2pi n/128))    [roll/hann/roll collapsed]
    // 4 independent cosine chains: u_{k+4} = 2cos(4a)*u_k - u_{k-4}  (ILP for dep latency)
    float irv;
    {
        float ang = (float)(2.0 * PI_D / 128.0) * (float)tid;
        float sn, c; __sincosf(ang, &sn, &c);
        float tcc = 2.0f * c;
        float u1 = c;
        float u2 = fmaf(tcc, u1, -1.0f);
        float u3 = fmaf(tcc, u2, -u1);
        float u4 = fmaf(tcc, u3, -u2);
        float u5 = fmaf(tcc, u4, -u3);
        float u6 = fmaf(tcc, u5, -u4);
        float u7 = fmaf(tcc, u6, -u5);
        float t0 = s_np[4] * u4;
        float t1 = fmaf(s_np[5], u5, s_np[1] * u1);
        float t2 = fmaf(s_np[6], u6, s_np[2] * u2);
        float t3 = fmaf(s_np[7], u7, s_np[3] * u3);
        float cc4  = fmaf(2.0f * u2, u2, -1.0f);   // cos(4a)
        float tc4a = 2.0f * cc4;
        float A0 = 1.0f, A1 = u1, A2 = u2, A3 = u3;   // u_{k-8}
        float B0 = u4,   B1 = u5, B2 = u6, B3 = u7;   // u_{k-4}
        #pragma unroll
        for (int g = 0; g < 14; ++g) {                // k = 8+4g+i, i=0..3 -> 8..63
            float n0 = fmaf(tc4a, B0, -A0); t0 = fmaf(s_np[8 + 4 * g + 0], n0, t0); A0 = B0; B0 = n0;
            float n1 = fmaf(tc4a, B1, -A1); t1 = fmaf(s_np[8 + 4 * g + 1], n1, t1); A1 = B1; B1 = n1;
            float n2 = fmaf(tc4a, B2, -A2); t2 = fmaf(s_np[8 + 4 * g + 2], n2, t2); A2 = B2; B2 = n2;
            float n3 = fmaf(tc4a, B3, -A3); t3 = fmaf(s_np[8 + 4 * g + 3], n3, t3); A3 = B3; B3 = n3;
        }
        float u64 = fmaf(tc4a, B0, -A0);              // chain0 state: B0=u60, A0=u56
        float tt = (t0 + t1) + (t2 + t3);
        float a = fmaf(2.0f, tt, s_np[0]);
        a = fmaf(s_np[64], u64, a);
        a *= (1.0f / 128.0f);
        a *= fmaf(0.5f, c, 0.5f);
        irv = a;
    }
    s_ir[tid] = irv;
    __syncthreads();                   // barrier 2: s_ir + s_famps visible

    // nz[p] = sum_{m<=p} noise[m] * ir[p-m], balanced split, m unrolled x2 so
    // adjacent s_ir reads fuse into ds_read2_b32 (same FP order as before).
    float accA = 0.0f;
    {
        int p1 = tid, h1 = (p1 + 2) >> 1;          // ceil((p1+1)/2)
        int m = 0;
        for (; m + 1 < h1; m += 2) {
            float i0 = s_ir[p1 - m], i1 = s_ir[p1 - m - 1];
            accA = fmaf(s_noise[m], i0, accA);
            accA = fmaf(s_noise[m + 1], i1, accA);
        }
        if (m < h1) accA = fmaf(s_noise[m], s_ir[p1 - m], accA);
    }
    {
        int p2 = 127 - tid, h2 = (p2 + 2) >> 1;
        float accB = 0.0f;
        int m = h2;
        for (; m + 1 <= p2; m += 2) {
            float i0 = s_ir[p2 - m], i1 = s_ir[p2 - m - 1];
            accB = fmaf(s_noise[m], i0, accB);
            accB = fmaf(s_noise[m + 1], i1, accB);
        }
        if (m <= p2) accB = fmaf(s_noise[m], s_ir[p2 - m], accB);
        s_red[p2] = accB;
    }
    __syncthreads();                   // barrier 3: nz partials
    float nzv = accA + s_red[tid];

    // harmonic synth: omega[n]/2pi = (128*prefix_excl + (r+1)*pitch)/sr; th = 2pi*frac
    // h = sum_k sin(k*th)*famps[k-1]; 4 independent sin chains:
    // s_{k+4} = 2cos(4th)*s_k - s_{k-4}  (seeds s1..s8)
    double q = (128.0 * prefix_b + (double)(tid + 1) * (double)pf) * (1.0 / 16000.0);
    float th = (float)(q - floor(q)) * (float)(2.0 * PI_D);  // exact for integer-k harmonics
    float h;
    {
        float s1v, c1v; __sincosf(th, &s1v, &c1v);
        float tc = 2.0f * c1v;
        float sk0 = s1v;                       // s1
        float sk1 = tc * s1v;                  // s2 (s0 = 0)
        float sk2 = fmaf(tc, sk1, -sk0);
        float sk3 = fmaf(tc, sk2, -sk1);
        float sk4 = fmaf(tc, sk3, -sk2);
        float sk5 = fmaf(tc, sk4, -sk3);
        float sk6 = fmaf(tc, sk5, -sk4);
        float sk7 = fmaf(tc, sk6, -sk5);
        float h0 = fmaf(sk4, s_famps[4], sk0 * s_famps[0]);
        float h1 = fmaf(sk5, s_famps[5], sk1 * s_famps[1]);
        float h2 = fmaf(sk6, s_famps[6], sk2 * s_famps[2]);
        float h3 = fmaf(sk7, s_famps[7], sk3 * s_famps[3]);
        float cs2 = fmaf(tc, c1v, -1.0f);      // cos(2th)
        float cs4 = fmaf(2.0f * cs2, cs2, -1.0f);
        float tc4 = 2.0f * cs4;
        float a0 = sk0, a1 = sk1, a2 = sk2, a3 = sk3;
        float b0 = sk4, b1 = sk5, b2 = sk6, b3 = sk7;
        #pragma unroll
        for (int g = 0; g < 23; ++g) {         // k = 9+4g+i, i=0..3 -> 9..100
            float n0 = fmaf(tc4, b0, -a0); h0 = fmaf(n0, s_famps[8 + 4 * g + 0], h0); a0 = b0; b0 = n0;
            float n1 = fmaf(tc4, b1, -a1); h1 = fmaf(n1, s_famps[8 + 4 * g + 1], h1); a1 = b1; b1 = n1;
            float n2 = fmaf(tc4, b2, -a2); h2 = fmaf(n2, s_famps[8 + 4 * g + 2], h2); a2 = b2; b2 = n2;
            float n3 = fmaf(tc4, b3, -a3); h3 = fmaf(n3, s_famps[8 + 4 * g + 3], h3); a3 = b3; b3 = n3;
        }
        h = (h0 + h1) + (h2 + h3);
    }
    sig[bf * BLK + tid] = h + nzv;
}

// --- FFT of packed signal frames (blocks 0..99, XCD-chunk-swizzled):
//     X[bm] = DIF_FFT(sigA + i*sigB)
//     + impulse-partition FFTs (blocks 100..107): H[p], scaled by 1/FFTN ---
__global__ __launch_bounds__(FTH) void k_fftsig(const float* __restrict__ sig,
                                                const float* __restrict__ rn,
                                                const float* __restrict__ decay,
                                                const float* __restrict__ wet,
                                                cplx* __restrict__ X,
                                                cplx* __restrict__ H) {
    __shared__ cplx sA[FFTN];
    int bid = blockIdx.x;
    int tid = threadIdx.x;

    if (bid >= NCONV) {
        // impulse partition p
        int p = bid - NCONV;
        double c  = log1p(exp(-(double)decay[0])) * (500.0 / (double)SRATE);
        double wg = 1.0 / (1.0 + exp(-(double)wet[0]));
        for (int i = tid; i < FFTN; i += FTH) {
            float v = 0.0f;
            if (i < HOP) {
                int t = p * HOP + i;
                if (t == 0)         v = 1.0f;
                else if (t < SRATE) v = rn[t] * (float)(exp(-c * (double)t) * wg);
            }
            sA[i] = make_float2(v, 0.0f);
        }
        fft8_dif<-1>(sA, tid);
        const float s = 1.0f / (float)FFTN;     // fold IFFT scale into H
        for (int i = tid; i < FFTN; i += FTH) {
            cplx v = sA[i];
            H[p * FFTN + i] = make_float2(v.x * s, v.y * s);
        }
        return;
    }

    int bm = conv_swz(bid);                      // same map as specmac -> X stays in-XCD L2
    int pb = bm / NHOPS, m = bm % NHOPS;
    const float* sa = sig + (2 * pb) * NSAMP;
    const float* sb = sa + NSAMP;
    int base = HOP * (m - 1);
    for (int i = tid; i < FFTN; i += FTH) {
        int idx = base + i;                      // idx < NSAMP guaranteed (m<=24)
        float va = 0.0f, vb = 0.0f;
        if (idx >= 0) { va = sa[idx]; vb = sb[idx]; }
        sA[i] = make_float2(va, vb);
    }
    fft8_dif<-1>(sA, tid);
    for (int i = tid; i < FFTN; i += FTH) X[bm * FFTN + i] = sA[i];
}

// --- Y = sum_p X[pb][m-p]*H[p] (digit-rev), IFFT, Re->batch 2pb, Im->batch 2pb+1 ---
__global__ __launch_bounds__(FTH) void k_specmac_ifft(const cplx* __restrict__ X,
                                                      const cplx* __restrict__ H,
                                                      float* __restrict__ out) {
    __shared__ cplx sA[FFTN];
    int bm = conv_swz(blockIdx.x);               // same map as fftsig (T1 locality)
    int pb = bm / NHOPS, m = bm % NHOPS;
    int tid = threadIdx.x;

    cplx acc[8];
    #pragma unroll
    for (int it = 0; it < 8; ++it) acc[it] = make_float2(0.0f, 0.0f);

    int pmax = (m < NPART - 1) ? m : (NPART - 1);
    for (int p = 0; p <= pmax; ++p) {
        const cplx* Xm = X + (pb * NHOPS + (m - p)) * FFTN;
        const cplx* Hp = H + p * FFTN;
        #pragma unroll
        for (int it = 0; it < 8; ++it) {
            int i = tid + (it << 9);
            cplx xv = Xm[i], hv = Hp[i];
            cplx pr = cmul(xv, hv);
            acc[it].x += pr.x; acc[it].y += pr.y;
        }
    }
    #pragma unroll
    for (int it = 0; it < 8; ++it) sA[tid + (it << 9)] = acc[it];

    fft8_dit<1>(sA, tid);          // digit-rev in -> natural out (scale folded into H)

    float* ob0 = out + (2 * pb) * NSAMP + m * HOP;
    float* ob1 = ob0 + NSAMP;
    #pragma unroll
    for (int it = 0; it < 4; ++it) {
        int j = tid + (it << 9);                 // [0,2048)
        cplx v = sA[HOP + j];                    // discard first half (overlap-save)
        ob0[j] = v.x;
        ob1[j] = v.y;
    }
}

extern "C" void kernel_launch(void* const* d_in, const int* in_sizes, int n_in,
                              void* d_out, int out_size, void* d_ws, size_t ws_size,
                              hipStream_t stream) {
    const float* amp_param   = (const float*)d_in[0];
    const float* noise_param = (const float*)d_in[1];
    const float* pitch       = (const float*)d_in[2];
    const float* noise       = (const float*)d_in[3];
    const float* rn          = (const float*)d_in[4];
    const float* decay       = (const float*)d_in[5];
    const float* wet         = (const float*)d_in[6];
    float* out = (float*)d_out;

    char* ws = (char*)d_ws;
    float*  sig    = (float*)(ws + OFF_SIG);
    cplx*   H      = (cplx*)(ws + OFF_H);
    cplx*   X      = (cplx*)(ws + OFF_X);

    k_synth<<<dim3(NBATCH * NFRAME), dim3(128), 0, stream>>>(amp_param, noise_param, pitch, noise, sig);
    k_fftsig<<<dim3(NCONV + NPART), dim3(FTH), 0, stream>>>(sig, rn, decay, wet, X, H);
    k_specmac_ifft<<<dim3(NCONV), dim3(FTH), 0, stream>>>(X, H, out);
}